// Round 14
// baseline (27.283 us; speedup 1.0000x reference)
//
#include <hip/hip_runtime.h>
#include <math.h>

// Depthwise max-plus 5x5 correlation, pad=2, stride=1, dilation=1.
//   imgs: (8,32,256,256) f32, kernel: (32,1,5,5) f32, out same shape.
#define BB 8
#define CC 32
#define HH 256
#define WW 256
#define TR 32              // output rows per block (amp = 36/32 = 1.125)
#define LR (TR + 4)        // staged LDS rows
#define LW (WW + 4)        // LDS row: 2-pad | 256 | 2-pad

typedef unsigned int u32;
typedef float f32x2 __attribute__((ext_vector_type(2)));
typedef float f32x4 __attribute__((ext_vector_type(4)));

__device__ __forceinline__ f32x2 pmax2(f32x2 a, f32x2 b) {
    return f32x2{fmaxf(a.x, b.x), fmaxf(a.y, b.y)};   // -> v_pk_max_f32
}

// R13 machinery (LDS stage, SGPR weights, packed pairs, XCD-chunked
// swizzle, early NT stores) at TR=32 with 512 THREADS: LDS 37.4KB -> 4
// blocks/CU x 8 waves = 32 waves/CU (full occupancy, fixing R10's 16),
// staging amp 1.25x -> 1.125x.
__global__ __launch_bounds__(512) void selconv_kernel(
    const float* __restrict__ imgs,
    const float* __restrict__ kern,
    float* __restrict__ out)
{
    __shared__ float lds[LR * LW];          // 37440 B -> 4 blocks/CU

    // XCD-chunked swizzle (2048 blocks, 8 XCDs, 256 per chunk; bijective).
    const int logical = (blockIdx.x & 7) * 256 + (blockIdx.x >> 3);

    const int t    = threadIdx.x;
    const int lane = t & 63;
    const int wv   = t >> 6;                // wave 0..7 (uniform)
    const int p    = logical >> 3;          // plane b*C + c (uniform)
    const int rt   = logical & 7;           // row tile (uniform)
    const int c    = p & (CC - 1);
    const int y0   = rt * TR;
    const int x    = lane * 4;

    const float NEG = -INFINITY;
    const float* plane = imgs + (size_t)p * (HH * WW);

    // ---- Stage 36 rows: waves 0..3 stage 5 rows, waves 4..7 stage 4 ----
    const int nstage = (wv < 4) ? 5 : 4;
    const int sbase  = (wv < 4) ? wv * 5 : 20 + (wv - 4) * 4;
    if (rt != 0 && rt != 7) {
#pragma unroll
        for (int i = 0; i < 5; ++i) {
            if (i < nstage) {
                const int L  = sbase + i;
                const int iy = y0 - 2 + L;
                __builtin_amdgcn_global_load_lds(
                    (const __attribute__((address_space(1))) u32*)(plane + iy * WW + x),
                    (__attribute__((address_space(3))) u32*)(&lds[L * LW + 2]),
                    16, 0, 0);
            }
        }
    } else {
#pragma unroll
        for (int i = 0; i < 5; ++i) {
            if (i < nstage) {
                const int L  = sbase + i;
                const int iy = y0 - 2 + L;
                if (iy >= 0 && iy < HH) {
                    __builtin_amdgcn_global_load_lds(
                        (const __attribute__((address_space(1))) u32*)(plane + iy * WW + x),
                        (__attribute__((address_space(3))) u32*)(&lds[L * LW + 2]),
                        16, 0, 0);
                } else {
                    *reinterpret_cast<float4*>(&lds[L * LW + 2 + x]) =
                        make_float4(NEG, NEG, NEG, NEG);
                }
            }
        }
    }

    // Left/right -inf pads: 36 rows x 4 cells, threads 0..143.
    if (t < LR * 4) {
        const int L = t >> 2;
        const int q = t & 3;
        const int col = (q < 2) ? q : (WW + q);          // 0,1,258,259
        lds[L * LW + col] = NEG;
    }

    // ---- Weights -> SGPRs; pairs wp[m][k] = {w[(m+1)*5+k], w[m*5+k]} ----
    float w[25];
    const float* kw = kern + c * 25;
#pragma unroll
    for (int i = 0; i < 25; ++i) {
        union { float f; int i; } u;
        u.f = kw[i];
        u.i = __builtin_amdgcn_readfirstlane(u.i);
        w[i] = u.f;
    }
    f32x2 wp[4][5];
#pragma unroll
    for (int m = 0; m < 4; ++m)
#pragma unroll
        for (int k = 0; k < 5; ++k)
            wp[m][k] = f32x2{w[(m + 1) * 5 + k], w[m * 5 + k]};

    __syncthreads();

    // ---- Compute: wave wv owns output rows (rel) 4*wv .. 4*wv+3 ----
    const int or0 = wv * 4;
    float* op = out + (size_t)p * (HH * WW) + (y0 + or0) * WW + x;

    // acc2[P][j] = {row 2P, row 2P+1} at col x+j
    f32x2 acc2[2][4];
#pragma unroll
    for (int P = 0; P < 2; ++P)
#pragma unroll
        for (int j = 0; j < 4; ++j) acc2[P][j] = f32x2{NEG, NEG};

    // Input rel row or0+dl; pair P (rows 2P,2P+1): d = dl-2P in [0,5];
    // d in 1..4 packed, d==0 / d==5 scalar halves.
#pragma unroll
    for (int dl = 0; dl < 8; ++dl) {
        const float* lrow = &lds[(or0 + dl) * LW];
        const float4 a = *reinterpret_cast<const float4*>(lrow + x);
        const float4 b = *reinterpret_cast<const float4*>(lrow + x + 4);
        const float v[8] = {a.x, a.y, a.z, a.w, b.x, b.y, b.z, b.w};

#pragma unroll
        for (int P = 0; P < 2; ++P) {
            const int d = dl - 2 * P;              // compile-time after unroll
            if (d >= 1 && d <= 4) {
                const int m = d - 1;
#pragma unroll
                for (int j = 0; j < 4; ++j) {
                    f32x2 t0 = f32x2{v[j + 0], v[j + 0]} + wp[m][0];
                    f32x2 t1 = f32x2{v[j + 1], v[j + 1]} + wp[m][1];
                    f32x2 t2 = f32x2{v[j + 2], v[j + 2]} + wp[m][2];
                    f32x2 t3 = f32x2{v[j + 3], v[j + 3]} + wp[m][3];
                    f32x2 t4 = f32x2{v[j + 4], v[j + 4]} + wp[m][4];
                    f32x2 mx = pmax2(pmax2(pmax2(t0, t1), pmax2(t2, t3)), t4);
                    acc2[P][j] = pmax2(acc2[P][j], mx);
                }
            } else if (d == 0) {                   // row 2P, ky = 0
#pragma unroll
                for (int j = 0; j < 4; ++j) {
                    const float s0 = v[j + 0] + w[0];
                    const float s1 = v[j + 1] + w[1];
                    const float s2 = v[j + 2] + w[2];
                    const float s3 = v[j + 3] + w[3];
                    const float s4 = v[j + 4] + w[4];
                    acc2[P][j].x = fmaxf(fmaxf(fmaxf(s0, s1), s2),
                                         fmaxf(fmaxf(s3, s4), acc2[P][j].x));
                }
            } else if (d == 5) {                   // row 2P+1, ky = 4
#pragma unroll
                for (int j = 0; j < 4; ++j) {
                    const float s0 = v[j + 0] + w[20];
                    const float s1 = v[j + 1] + w[21];
                    const float s2 = v[j + 2] + w[22];
                    const float s3 = v[j + 3] + w[23];
                    const float s4 = v[j + 4] + w[24];
                    acc2[P][j].y = fmaxf(fmaxf(fmaxf(s0, s1), s2),
                                         fmaxf(fmaxf(s3, s4), acc2[P][j].y));
                }
            }
        }

        // Pair P final once dl == 2P+5: store rows 2P, 2P+1 (non-temporal).
#pragma unroll
        for (int P = 0; P < 2; ++P) {
            if (dl == 2 * P + 5) {
                f32x4 lo = {acc2[P][0].x, acc2[P][1].x, acc2[P][2].x, acc2[P][3].x};
                f32x4 hi = {acc2[P][0].y, acc2[P][1].y, acc2[P][2].y, acc2[P][3].y};
                __builtin_nontemporal_store(
                    lo, reinterpret_cast<f32x4*>(op + (2 * P) * WW));
                __builtin_nontemporal_store(
                    hi, reinterpret_cast<f32x4*>(op + (2 * P + 1) * WW));
            }
        }
    }
}

extern "C" void kernel_launch(void* const* d_in, const int* in_sizes, int n_in,
                              void* d_out, int out_size, void* d_ws, size_t ws_size,
                              hipStream_t stream)
{
    const float* imgs = (const float*)d_in[0];
    const float* kern = (const float*)d_in[1];
    float* out = (float*)d_out;

    const int blocks = BB * CC * (HH / TR);   // 2048 (multiple of 8)
    selconv_kernel<<<blocks, 512, 0, stream>>>(imgs, kern, out);
}

// Round 15
// 26.465 us; speedup vs baseline: 1.0309x; 1.0309x over previous
//
#include <hip/hip_runtime.h>
#include <math.h>

// Depthwise max-plus 5x5 correlation, pad=2, stride=1, dilation=1.
//   imgs: (8,32,256,256) f32, kernel: (32,1,5,5) f32, out same shape.
//
// FINAL (R13 config, 26.6us): LDS stage via global_load_lds + -inf padded
// rows + SGPR weights + row-pair packed v_pk_add/max compute + XCD-chunked
// block swizzle + early per-pair NON-TEMPORAL stores.
// Empirical roofline: 128MB compulsory mixed read+write traffic at
// ~4.8 TB/s effective (~76% of the 6.3-6.9 TB/s single-direction ceiling).
// Traffic-reduction A/Bs (TR=32 @256thr R10, @512thr R14) were null/negative;
// only memory-stream levers (swizzle/NT/interleave) moved the floor.
#define BB 8
#define CC 32
#define HH 256
#define WW 256
#define TR 16              // output rows per block
#define LR (TR + 4)        // staged LDS rows (2+2 vertical halo)
#define LW (WW + 4)        // LDS row: 2-pad | 256 | 2-pad

typedef unsigned int u32;
typedef float f32x2 __attribute__((ext_vector_type(2)));
typedef float f32x4 __attribute__((ext_vector_type(4)));   // nt-store compatible

__device__ __forceinline__ f32x2 pmax2(f32x2 a, f32x2 b) {
    return f32x2{fmaxf(a.x, b.x), fmaxf(a.y, b.y)};   // -> v_pk_max_f32
}

__global__ __launch_bounds__(256) void selconv_kernel(
    const float* __restrict__ imgs,
    const float* __restrict__ kern,
    float* __restrict__ out)
{
    __shared__ float lds[LR * LW];          // 20800 B -> 7 blocks/CU

    // XCD-chunked swizzle (4096 blocks, 8 XCDs, 512 per chunk; bijective).
    const int logical = (blockIdx.x & 7) * 512 + (blockIdx.x >> 3);

    const int t    = threadIdx.x;
    const int lane = t & 63;
    const int wv   = t >> 6;                // wave 0..3 (uniform)
    const int p    = logical >> 4;          // plane b*C + c (uniform)
    const int rt   = logical & 15;          // row tile (uniform)
    const int c    = p & (CC - 1);
    const int y0   = rt * TR;
    const int x    = lane * 4;

    const float NEG = -INFINITY;
    const float* plane = imgs + (size_t)p * (HH * WW);

    // ---- Stage 20 rows: wave wv stages LDS rows 5*wv .. 5*wv+4 ----
    if (rt != 0 && rt != 15) {
#pragma unroll
        for (int i = 0; i < 5; ++i) {
            const int L  = wv * 5 + i;
            const int iy = y0 - 2 + L;
            __builtin_amdgcn_global_load_lds(
                (const __attribute__((address_space(1))) u32*)(plane + iy * WW + x),
                (__attribute__((address_space(3))) u32*)(&lds[L * LW + 2]),
                16, 0, 0);
        }
    } else {
#pragma unroll
        for (int i = 0; i < 5; ++i) {
            const int L  = wv * 5 + i;
            const int iy = y0 - 2 + L;
            if (iy >= 0 && iy < HH) {
                __builtin_amdgcn_global_load_lds(
                    (const __attribute__((address_space(1))) u32*)(plane + iy * WW + x),
                    (__attribute__((address_space(3))) u32*)(&lds[L * LW + 2]),
                    16, 0, 0);
            } else {
                *reinterpret_cast<float4*>(&lds[L * LW + 2 + x]) =
                    make_float4(NEG, NEG, NEG, NEG);
            }
        }
    }

    // Left/right -inf pads: 20 rows x 4 cells, threads 0..79.
    if (t < LR * 4) {
        const int L = t >> 2;
        const int q = t & 3;
        const int col = (q < 2) ? q : (WW + q);          // 0,1,258,259
        lds[L * LW + col] = NEG;
    }

    // ---- Weights -> SGPRs; pairs wp[m][k] = {w[(m+1)*5+k], w[m*5+k]} ----
    float w[25];
    const float* kw = kern + c * 25;
#pragma unroll
    for (int i = 0; i < 25; ++i) {
        union { float f; int i; } u;
        u.f = kw[i];
        u.i = __builtin_amdgcn_readfirstlane(u.i);
        w[i] = u.f;
    }
    f32x2 wp[4][5];
#pragma unroll
    for (int m = 0; m < 4; ++m)
#pragma unroll
        for (int k = 0; k < 5; ++k)
            wp[m][k] = f32x2{w[(m + 1) * 5 + k], w[m * 5 + k]};

    __syncthreads();

    // ---- Compute: wave wv owns output rows (rel) 4*wv .. 4*wv+3 ----
    const int or0 = wv * 4;
    float* op = out + (size_t)p * (HH * WW) + (y0 + or0) * WW + x;

    // acc2[P][j] = {row 2P, row 2P+1} at col x+j
    f32x2 acc2[2][4];
#pragma unroll
    for (int P = 0; P < 2; ++P)
#pragma unroll
        for (int j = 0; j < 4; ++j) acc2[P][j] = f32x2{NEG, NEG};

    // Input rel row or0+dl; pair P (rows 2P,2P+1): d = dl-2P in [0,5];
    // d in 1..4 packed, d==0 / d==5 scalar halves.
#pragma unroll
    for (int dl = 0; dl < 8; ++dl) {
        const float* lrow = &lds[(or0 + dl) * LW];
        const float4 a = *reinterpret_cast<const float4*>(lrow + x);
        const float4 b = *reinterpret_cast<const float4*>(lrow + x + 4);
        const float v[8] = {a.x, a.y, a.z, a.w, b.x, b.y, b.z, b.w};

#pragma unroll
        for (int P = 0; P < 2; ++P) {
            const int d = dl - 2 * P;              // compile-time after unroll
            if (d >= 1 && d <= 4) {
                const int m = d - 1;
#pragma unroll
                for (int j = 0; j < 4; ++j) {
                    f32x2 t0 = f32x2{v[j + 0], v[j + 0]} + wp[m][0];
                    f32x2 t1 = f32x2{v[j + 1], v[j + 1]} + wp[m][1];
                    f32x2 t2 = f32x2{v[j + 2], v[j + 2]} + wp[m][2];
                    f32x2 t3 = f32x2{v[j + 3], v[j + 3]} + wp[m][3];
                    f32x2 t4 = f32x2{v[j + 4], v[j + 4]} + wp[m][4];
                    f32x2 mx = pmax2(pmax2(pmax2(t0, t1), pmax2(t2, t3)), t4);
                    acc2[P][j] = pmax2(acc2[P][j], mx);
                }
            } else if (d == 0) {                   // row 2P, ky = 0
#pragma unroll
                for (int j = 0; j < 4; ++j) {
                    const float s0 = v[j + 0] + w[0];
                    const float s1 = v[j + 1] + w[1];
                    const float s2 = v[j + 2] + w[2];
                    const float s3 = v[j + 3] + w[3];
                    const float s4 = v[j + 4] + w[4];
                    acc2[P][j].x = fmaxf(fmaxf(fmaxf(s0, s1), s2),
                                         fmaxf(fmaxf(s3, s4), acc2[P][j].x));
                }
            } else if (d == 5) {                   // row 2P+1, ky = 4
#pragma unroll
                for (int j = 0; j < 4; ++j) {
                    const float s0 = v[j + 0] + w[20];
                    const float s1 = v[j + 1] + w[21];
                    const float s2 = v[j + 2] + w[22];
                    const float s3 = v[j + 3] + w[23];
                    const float s4 = v[j + 4] + w[24];
                    acc2[P][j].y = fmaxf(fmaxf(fmaxf(s0, s1), s2),
                                         fmaxf(fmaxf(s3, s4), acc2[P][j].y));
                }
            }
        }

        // Pair P final once dl == 2P+5: store rows 2P, 2P+1 (non-temporal).
#pragma unroll
        for (int P = 0; P < 2; ++P) {
            if (dl == 2 * P + 5) {
                f32x4 lo = {acc2[P][0].x, acc2[P][1].x, acc2[P][2].x, acc2[P][3].x};
                f32x4 hi = {acc2[P][0].y, acc2[P][1].y, acc2[P][2].y, acc2[P][3].y};
                __builtin_nontemporal_store(
                    lo, reinterpret_cast<f32x4*>(op + (2 * P) * WW));
                __builtin_nontemporal_store(
                    hi, reinterpret_cast<f32x4*>(op + (2 * P + 1) * WW));
            }
        }
    }
}

extern "C" void kernel_launch(void* const* d_in, const int* in_sizes, int n_in,
                              void* d_out, int out_size, void* d_ws, size_t ws_size,
                              hipStream_t stream)
{
    const float* imgs = (const float*)d_in[0];
    const float* kern = (const float*)d_in[1];
    float* out = (float*)d_out;

    const int blocks = BB * CC * (HH / TR);   // 4096 (multiple of 8)
    selconv_kernel<<<blocks, 256, 0, stream>>>(imgs, kern, out);
}